// Round 7
// baseline (106.316 us; speedup 1.0000x reference)
//
#include <hip/hip_runtime.h>
#include <stdint.h>

#define DIM     300
#define NBATCH  4096
#define RTOK    32
#define NSUP    64      // N*S = 2*32 support cols
#define KP      320     // B K padded to 10*32
#define SMST    82      // padded sm tile x-stride (floats)
#define SMY     36      // per-channel y extent

typedef float f32x4 __attribute__((ext_vector_type(4)));
typedef short s16x8 __attribute__((ext_vector_type(8)));

static __device__ __forceinline__ unsigned bc(float x) { return __builtin_bit_cast(unsigned, x); }
static __device__ __forceinline__ float asf(unsigned u) { return __builtin_bit_cast(float, u); }
static __device__ __forceinline__ unsigned perm_hi(unsigned a, unsigned b) {
    return __builtin_amdgcn_perm(a, b, 0x07060302u);   // [a.hi16 : b.hi16], b -> low short
}
static __device__ __forceinline__ unsigned short f2bf(float x) {   // RNE (prep only)
    unsigned u = bc(x);
    return (unsigned short)((u + 0x7FFFu + ((u >> 16) & 1u)) >> 16);
}
static __device__ __forceinline__ float bf2f(unsigned short h) { return asf((unsigned)h << 16); }

struct AB { s16x8 h, l; };
// split f32x8 -> bf16 hi (round-half-up) + bf16 lo (round-half-up of exact residual)
static __device__ __forceinline__ AB cvt_split(float4 c0, float4 c1, float& nrm) {
    nrm = fmaf(c0.x, c0.x, nrm); nrm = fmaf(c0.y, c0.y, nrm);
    nrm = fmaf(c0.z, c0.z, nrm); nrm = fmaf(c0.w, c0.w, nrm);
    nrm = fmaf(c1.x, c1.x, nrm); nrm = fmaf(c1.y, c1.y, nrm);
    nrm = fmaf(c1.z, c1.z, nrm); nrm = fmaf(c1.w, c1.w, nrm);
    const unsigned u0 = bc(c0.x) + 0x8000u, u1 = bc(c0.y) + 0x8000u;
    const unsigned u2 = bc(c0.z) + 0x8000u, u3 = bc(c0.w) + 0x8000u;
    const unsigned u4 = bc(c1.x) + 0x8000u, u5 = bc(c1.y) + 0x8000u;
    const unsigned u6 = bc(c1.z) + 0x8000u, u7 = bc(c1.w) + 0x8000u;
    const float r0 = c0.x - asf(u0 & 0xffff0000u), r1 = c0.y - asf(u1 & 0xffff0000u);
    const float r2 = c0.z - asf(u2 & 0xffff0000u), r3 = c0.w - asf(u3 & 0xffff0000u);
    const float r4 = c1.x - asf(u4 & 0xffff0000u), r5 = c1.y - asf(u5 & 0xffff0000u);
    const float r6 = c1.z - asf(u6 & 0xffff0000u), r7 = c1.w - asf(u7 & 0xffff0000u);
    union { s16x8 v; unsigned u[4]; } H, L;
    H.u[0] = perm_hi(u1, u0); H.u[1] = perm_hi(u3, u2);
    H.u[2] = perm_hi(u5, u4); H.u[3] = perm_hi(u7, u6);
    L.u[0] = perm_hi(bc(r1) + 0x8000u, bc(r0) + 0x8000u);
    L.u[1] = perm_hi(bc(r3) + 0x8000u, bc(r2) + 0x8000u);
    L.u[2] = perm_hi(bc(r5) + 0x8000u, bc(r4) + 0x8000u);
    L.u[3] = perm_hi(bc(r7) + 0x8000u, bc(r6) + 0x8000u);
    AB r; r.h = H.v; r.l = L.v; return r;
}

// ---------------- kernel 1: normalize support vectors -> bf16 hi/lo [64][320]
__global__ __launch_bounds__(64) void prep_kernel(
    const int* __restrict__ sidx, const float* __restrict__ emb,
    unsigned short* __restrict__ Bh, unsigned short* __restrict__ Bl) {
    const int j = blockIdx.x, l = threadIdx.x;
    const size_t tok = (size_t)sidx[j];
    const float* src = emb + tok * DIM;
    float e[5];
    #pragma unroll
    for (int c = 0; c < 5; ++c) {
        const int k = c * 64 + l;
        e[c] = (k < DIM) ? src[k] : 0.f;
    }
    float s = e[0]*e[0] + e[1]*e[1] + e[2]*e[2] + e[3]*e[3] + e[4]*e[4];
    #pragma unroll
    for (int m = 32; m >= 1; m >>= 1) s += __shfl_xor(s, m);
    const float rn = 1.f / fmaxf(sqrtf(s), 1e-8f);
    #pragma unroll
    for (int c = 0; c < 5; ++c) {
        const int k = c * 64 + l;
        const float v = (k < DIM) ? e[c] * rn : 0.f;
        const unsigned short h = f2bf(v);
        Bh[j * KP + k] = h;
        Bl[j * KP + k] = f2bf(v - bf2f(h));
    }
}

// ---------------- kernel 2: A-direct-from-global split-bf16 MFMA GEMM + fused tail
// 256 threads / 4 waves; wave w: rows (w>>1)*16.., cols (w&1)*32.. (two 16-col tiles)
__global__ __launch_bounds__(256) void main_kernel(
    const int* __restrict__ tokens, const float* __restrict__ emb,
    const unsigned short* __restrict__ Bh, const unsigned short* __restrict__ Bl,
    const float* __restrict__ c1w, const float* __restrict__ c1b,
    const float* __restrict__ c2w, const float* __restrict__ c2b,
    const float* __restrict__ f2w, const float* __restrict__ f2b,
    const float* __restrict__ fcw, const float* __restrict__ fcb,
    float* __restrict__ out) {

    __shared__ __attribute__((aligned(16))) float smP[34 * SMST];  // [xp=r+1][ch][yp=s+1]
    __shared__ __attribute__((aligned(16))) float pl1P[2 * 17 * 18];
    __shared__ float scrP[8];    // [0..3]=se_w, [4..7]=sv_w

    const int tid = threadIdx.x;
    const int w = tid >> 6, l = tid & 63;
    const int batch = blockIdx.x;
    const int c = l & 15, hq = l >> 4;
    const int rb = (w >> 1) * 16;
    const int cbase = (w & 1) * 32;
    const int ch = w & 1;

    // ---- P0: clear smP (borders matter; interior rewritten) + pl1 borders
    {
        const f32x4 z = {0.f, 0.f, 0.f, 0.f};
        #pragma unroll
        for (int i = 0; i < 3; ++i) {
            const int idx = i * 256 + tid;
            if (idx < 697) ((f32x4*)smP)[idx] = z;
        }
        if (tid >= 190 && tid < 256) {
            const int z2 = tid - 190;
            const int ic = (z2 >= 33) ? 1 : 0;
            const int rm = z2 - 33 * ic;
            pl1P[ic * 306 + (rm < 17 ? rm : (rm - 16) * 18)] = 0.f;
        }
    }
    __syncthreads();   // BAR0 (cheap: LDS-only)

    // ---- P1: GEMM. A streamed from emb (f32 -> in-reg split-bf16), B from ws.
    const size_t tok = (size_t)tokens[batch * RTOK + rb + c];
    const float* srcA = emb + tok * DIM;
    const unsigned short* pBh0 = Bh + (cbase + c) * KP + hq * 8;
    const unsigned short* pBl0 = Bl + (cbase + c) * KP + hq * 8;
    const unsigned short* pBh1 = pBh0 + 16 * KP;
    const unsigned short* pBl1 = pBl0 + 16 * KP;

    f32x4 q00 = {0,0,0,0}, q01 = {0,0,0,0}, q02 = {0,0,0,0};
    f32x4 q10 = {0,0,0,0}, q11 = {0,0,0,0}, q12 = {0,0,0,0};
    float nrm = 0.f;

    #pragma unroll
    for (int t = 0; t < 9; ++t) {
        const float4 c0 = *(const float4*)(srcA + t * 32 + hq * 8);
        const float4 c1 = *(const float4*)(srcA + t * 32 + hq * 8 + 4);
        const s16x8 bh0 = *(const s16x8*)(pBh0 + t * 32);
        const s16x8 bl0 = *(const s16x8*)(pBl0 + t * 32);
        const s16x8 bh1 = *(const s16x8*)(pBh1 + t * 32);
        const s16x8 bl1 = *(const s16x8*)(pBl1 + t * 32);
        const AB a = cvt_split(c0, c1, nrm);
        q00 = __builtin_amdgcn_mfma_f32_16x16x32_bf16(a.h, bh0, q00, 0, 0, 0);
        q01 = __builtin_amdgcn_mfma_f32_16x16x32_bf16(a.h, bl0, q01, 0, 0, 0);
        q02 = __builtin_amdgcn_mfma_f32_16x16x32_bf16(a.l, bh0, q02, 0, 0, 0);
        q10 = __builtin_amdgcn_mfma_f32_16x16x32_bf16(a.h, bh1, q10, 0, 0, 0);
        q11 = __builtin_amdgcn_mfma_f32_16x16x32_bf16(a.h, bl1, q11, 0, 0, 0);
        q12 = __builtin_amdgcn_mfma_f32_16x16x32_bf16(a.l, bh1, q12, 0, 0, 0);
    }
    {   // t = 9: k = 288 + hq*8 .. +7; valid k < 300; clamped in-bounds loads + mask
        const float* pc = srcA + ((hq == 0) ? 288 : 292);
        const float4 c0 = *(const float4*)(pc);
        const float4 c1 = *(const float4*)(pc + 4);
        float4 d0, d1;
        d0.x = (hq == 0) ? c0.x : ((hq == 1) ? c1.x : 0.f);
        d0.y = (hq == 0) ? c0.y : ((hq == 1) ? c1.y : 0.f);
        d0.z = (hq == 0) ? c0.z : ((hq == 1) ? c1.z : 0.f);
        d0.w = (hq == 0) ? c0.w : ((hq == 1) ? c1.w : 0.f);
        d1.x = (hq == 0) ? c1.x : 0.f;
        d1.y = (hq == 0) ? c1.y : 0.f;
        d1.z = (hq == 0) ? c1.z : 0.f;
        d1.w = (hq == 0) ? c1.w : 0.f;
        const s16x8 bh0 = *(const s16x8*)(pBh0 + 288);
        const s16x8 bl0 = *(const s16x8*)(pBl0 + 288);
        const s16x8 bh1 = *(const s16x8*)(pBh1 + 288);
        const s16x8 bl1 = *(const s16x8*)(pBl1 + 288);
        const AB a = cvt_split(d0, d1, nrm);
        q00 = __builtin_amdgcn_mfma_f32_16x16x32_bf16(a.h, bh0, q00, 0, 0, 0);
        q01 = __builtin_amdgcn_mfma_f32_16x16x32_bf16(a.h, bl0, q01, 0, 0, 0);
        q02 = __builtin_amdgcn_mfma_f32_16x16x32_bf16(a.l, bh0, q02, 0, 0, 0);
        q10 = __builtin_amdgcn_mfma_f32_16x16x32_bf16(a.h, bh1, q10, 0, 0, 0);
        q11 = __builtin_amdgcn_mfma_f32_16x16x32_bf16(a.h, bl1, q11, 0, 0, 0);
        q12 = __builtin_amdgcn_mfma_f32_16x16x32_bf16(a.l, bh1, q12, 0, 0, 0);
    }

    // ---- P2: norms (exact f32) + scale + smP writes + fused softmax partials
    {
        nrm += __shfl_xor(nrm, 16);
        nrm += __shfl_xor(nrm, 32);            // every lane: full |row rb+c|^2
        float se = 0.f, sv = 0.f;
        #pragma unroll
        for (int q = 0; q < 4; ++q) {
            const float nq = __shfl(nrm, hq * 4 + q);   // norm of row rb+hq*4+q
            const float rn = __builtin_amdgcn_rcpf(
                fmaxf(__builtin_amdgcn_sqrtf(nq), 1e-8f));
            const float v0 = (q00[q] + q01[q] + q02[q]) * rn;
            const float v1 = (q10[q] + q11[q] + q12[q]) * rn;
            const int row = rb + hq * 4 + q;
            smP[(row + 1) * SMST + ch * SMY + (c + 1)]  = v0;   // s = c
            smP[(row + 1) * SMST + ch * SMY + (c + 17)] = v1;   // s = 16 + c
            const float e0 = __expf(v0), e1 = __expf(v1);       // |v|<=1: no max-shift
            se += e0 + e1;
            sv = fmaf(e0, v0, sv); sv = fmaf(e1, v1, sv);
        }
        #pragma unroll
        for (int m = 32; m >= 1; m >>= 1) { se += __shfl_xor(se, m); sv += __shfl_xor(sv, m); }
        if (l == 0) { scrP[w] = se; scrP[4 + w] = sv; }
    }
    __syncthreads();   // BAR1: smP + softmax partials ready

    // ---- P3: conv1 (both oc per thread) + gate + relu + maxpool -> pl1P
    {
        const int ii = tid >> 4, jj = tid & 15;
        float pc0[4] = {0,0,0,0}, pc1[4] = {0,0,0,0};   // per-oc, gated-combined below
        float pA0[4] = {0,0,0,0}, pA1[4] = {0,0,0,0};   // oc0/oc1 partials for ic=1
        #pragma unroll
        for (int ic = 0; ic < 2; ++ic) {
            float p[4][4];
            #pragma unroll
            for (int a = 0; a < 4; ++a) {        // xp = 2jj+a, yp base 2ii
                const int off = (2 * jj + a) * SMST + ic * SMY + 2 * ii;
                const float2 v01 = *(const float2*)&smP[off];
                const float2 v23 = *(const float2*)&smP[off + 2];
                p[a][0] = v01.x; p[a][1] = v01.y; p[a][2] = v23.x; p[a][3] = v23.y;
            }
            #pragma unroll
            for (int py = 0; py < 2; ++py)
            #pragma unroll
            for (int px = 0; px < 2; ++px)
            #pragma unroll
            for (int dy = 0; dy < 3; ++dy)
            #pragma unroll
            for (int dx = 0; dx < 3; ++dx) {
                const float pv = p[px + dx][py + dy];
                const int pos = py * 2 + px;
                if (ic == 0) {
                    pc0[pos] = fmaf(c1w[0 * 9 + dy * 3 + dx], pv, pc0[pos]);
                    pc1[pos] = fmaf(c1w[2 * 9 + dy * 3 + dx], pv, pc1[pos]);
                } else {
                    pA0[pos] = fmaf(c1w[1 * 9 + dy * 3 + dx], pv, pA0[pos]);
                    pA1[pos] = fmaf(c1w[3 * 9 + dy * 3 + dx], pv, pA1[pos]);
                }
            }
        }
        const float p0 = (scrP[4] + scrP[6]) / (scrP[0] + scrP[2]);
        const float p1 = (scrP[5] + scrP[7]) / (scrP[1] + scrP[3]);
        const float gg0 = 1.f / (1.f + __expf(-(f2w[0] * p0 + f2w[1] * p1 + f2b[0])));
        const float gg1 = 1.f / (1.f + __expf(-(f2w[2] * p0 + f2w[3] * p1 + f2b[1])));
        const float b0 = c1b[0], b1 = c1b[1];
        float mx0 = 0.f, mx1 = 0.f;   // relu folded
        #pragma unroll
        for (int i = 0; i < 4; ++i) {
            mx0 = fmaxf(mx0, b0 + gg0 * pc0[i] + gg1 * pA0[i]);
            mx1 = fmaxf(mx1, b1 + gg0 * pc1[i] + gg1 * pA1[i]);
        }
        pl1P[0 * 306 + (ii + 1) * 18 + (jj + 1)] = mx0;
        pl1P[1 * 306 + (ii + 1) * 18 + (jj + 1)] = mx1;
    }
    __syncthreads();   // BAR2: pl1P ready

    // ---- P4: wave 0: conv2(2x2,pad1)+relu+avgpool2 + fc -> out
    if (w == 0) {
        float o0 = 0.f, o1 = 0.f;
        #pragma unroll
        for (int h = 0; h < 2; ++h) {
            const int o = h * 64 + l, oc2 = o >> 6, ii2 = (o >> 3) & 7, jj2 = o & 7;
            float sum = 0.f;
            #pragma unroll
            for (int py = 0; py < 2; ++py)
            #pragma unroll
            for (int px = 0; px < 2; ++px) {
                const int y = 2 * ii2 + py, x = 2 * jj2 + px;
                float acc = c2b[oc2];
                #pragma unroll
                for (int ic = 0; ic < 2; ++ic)
                #pragma unroll
                for (int dy = 0; dy < 2; ++dy)
                #pragma unroll
                for (int dx = 0; dx < 2; ++dx)
                    acc += c2w[((oc2 * 2 + ic) * 2 + dy) * 2 + dx] *
                           pl1P[ic * 306 + (y + dy) * 18 + (x + dx)];
                sum += fmaxf(acc, 0.f);
            }
            const float val = 0.25f * sum;
            o0 = fmaf(val, fcw[o], o0);
            o1 = fmaf(val, fcw[128 + o], o1);
        }
        #pragma unroll
        for (int m = 32; m >= 1; m >>= 1) { o0 += __shfl_xor(o0, m); o1 += __shfl_xor(o1, m); }
        if (l == 0) {
            out[batch * 2 + 0] = fcb[0] + o0;
            out[batch * 2 + 1] = fcb[1] + o1;
        }
    }
}

extern "C" void kernel_launch(void* const* d_in, const int* in_sizes, int n_in,
                              void* d_out, int out_size, void* d_ws, size_t ws_size,
                              hipStream_t stream) {
    const int* tokens = (const int*)d_in[0];
    const int* sidx   = (const int*)d_in[1];
    const float* emb  = (const float*)d_in[2];
    const float* c1w  = (const float*)d_in[3];
    const float* c1b  = (const float*)d_in[4];
    const float* c2w  = (const float*)d_in[5];
    const float* c2b  = (const float*)d_in[6];
    const float* f2w  = (const float*)d_in[7];
    const float* f2b  = (const float*)d_in[8];
    const float* fcw  = (const float*)d_in[9];
    const float* fcb  = (const float*)d_in[10];

    unsigned short* Bh = (unsigned short*)d_ws;
    unsigned short* Bl = Bh + NSUP * KP;

    prep_kernel<<<NSUP, 64, 0, stream>>>(sidx, emb, Bh, Bl);
    main_kernel<<<NBATCH, 256, 0, stream>>>(tokens, emb, Bh, Bl,
                                            c1w, c1b, c2w, c2b,
                                            f2w, f2b, fcw, fcb, (float*)d_out);
}

// Round 8
// 83.097 us; speedup vs baseline: 1.2794x; 1.2794x over previous
//
#include <hip/hip_runtime.h>
#include <stdint.h>

#define DIM     300
#define NBATCH  4096
#define NSUP    64      // N*S = 2*32 support cols
#define KP      320     // B K padded to 10*32
#define ASTF    332     // A LDS row stride in floats (16B-aligned rows, 2-way banks)
#define SMST    82      // padded sm tile x-stride (floats)
#define SMY     36      // per-channel y extent

typedef float f32x4 __attribute__((ext_vector_type(4)));
typedef short s16x8 __attribute__((ext_vector_type(8)));

static __device__ __forceinline__ unsigned bc(float x) { return __builtin_bit_cast(unsigned, x); }
static __device__ __forceinline__ float asf(unsigned u) { return __builtin_bit_cast(float, u); }
static __device__ __forceinline__ unsigned perm_hi(unsigned a, unsigned b) {
    return __builtin_amdgcn_perm(a, b, 0x07060302u);   // [a.hi16 : b.hi16]
}
static __device__ __forceinline__ unsigned short f2bf(float x) {   // RNE (prep only)
    unsigned u = bc(x);
    return (unsigned short)((u + 0x7FFFu + ((u >> 16) & 1u)) >> 16);
}
static __device__ __forceinline__ float bf2f(unsigned short h) { return asf((unsigned)h << 16); }

struct AB { s16x8 h, l; };
// split f32x8 -> bf16 hi (round-half-up) + bf16 lo (residual); accumulates sum of squares
static __device__ __forceinline__ AB cvt_split(float4 c0, float4 c1, float& nrm) {
    nrm = fmaf(c0.x, c0.x, nrm); nrm = fmaf(c0.y, c0.y, nrm);
    nrm = fmaf(c0.z, c0.z, nrm); nrm = fmaf(c0.w, c0.w, nrm);
    nrm = fmaf(c1.x, c1.x, nrm); nrm = fmaf(c1.y, c1.y, nrm);
    nrm = fmaf(c1.z, c1.z, nrm); nrm = fmaf(c1.w, c1.w, nrm);
    const unsigned u0 = bc(c0.x) + 0x8000u, u1 = bc(c0.y) + 0x8000u;
    const unsigned u2 = bc(c0.z) + 0x8000u, u3 = bc(c0.w) + 0x8000u;
    const unsigned u4 = bc(c1.x) + 0x8000u, u5 = bc(c1.y) + 0x8000u;
    const unsigned u6 = bc(c1.z) + 0x8000u, u7 = bc(c1.w) + 0x8000u;
    const float r0 = c0.x - asf(u0 & 0xffff0000u), r1 = c0.y - asf(u1 & 0xffff0000u);
    const float r2 = c0.z - asf(u2 & 0xffff0000u), r3 = c0.w - asf(u3 & 0xffff0000u);
    const float r4 = c1.x - asf(u4 & 0xffff0000u), r5 = c1.y - asf(u5 & 0xffff0000u);
    const float r6 = c1.z - asf(u6 & 0xffff0000u), r7 = c1.w - asf(u7 & 0xffff0000u);
    union { s16x8 v; unsigned u[4]; } H, L;
    H.u[0] = perm_hi(u1, u0); H.u[1] = perm_hi(u3, u2);
    H.u[2] = perm_hi(u5, u4); H.u[3] = perm_hi(u7, u6);
    L.u[0] = perm_hi(bc(r1) + 0x8000u, bc(r0) + 0x8000u);
    L.u[1] = perm_hi(bc(r3) + 0x8000u, bc(r2) + 0x8000u);
    L.u[2] = perm_hi(bc(r5) + 0x8000u, bc(r4) + 0x8000u);
    L.u[3] = perm_hi(bc(r7) + 0x8000u, bc(r6) + 0x8000u);
    AB r; r.h = H.v; r.l = L.v; return r;
}

// ---------------- kernel 1: normalize support vectors -> bf16 hi/lo [64][320]
__global__ __launch_bounds__(64) void prep_kernel(
    const int* __restrict__ sidx, const float* __restrict__ emb,
    unsigned short* __restrict__ Bh, unsigned short* __restrict__ Bl) {
    const int j = blockIdx.x, l = threadIdx.x;
    const size_t tok = (size_t)sidx[j];
    const float* src = emb + tok * DIM;
    float e[5];
    #pragma unroll
    for (int c = 0; c < 5; ++c) {
        const int k = c * 64 + l;
        e[c] = (k < DIM) ? src[k] : 0.f;
    }
    float s = e[0]*e[0] + e[1]*e[1] + e[2]*e[2] + e[3]*e[3] + e[4]*e[4];
    #pragma unroll
    for (int m = 32; m >= 1; m >>= 1) s += __shfl_xor(s, m);
    const float rn = 1.f / fmaxf(sqrtf(s), 1e-8f);
    #pragma unroll
    for (int c = 0; c < 5; ++c) {
        const int k = c * 64 + l;
        const float v = (k < DIM) ? e[c] * rn : 0.f;
        const unsigned short h = f2bf(v);
        Bh[j * KP + k] = h;
        Bl[j * KP + k] = f2bf(v - bf2f(h));
    }
}

// ---------------- kernel 2: gather-GEMM, 8 batch-panels/block, async-split staging
// 512 thr / 8 waves; wave w: rows (w>>2)*16, cols (w&3)*16 of the 32x64 panel
__global__ __launch_bounds__(512) void gemm_kernel(
    const int* __restrict__ tokens, const float* __restrict__ emb,
    const unsigned short* __restrict__ Bh, const unsigned short* __restrict__ Bl,
    float* __restrict__ smG) {

    __shared__ __attribute__((aligned(16))) float A[32 * ASTF];   // 42.5 KB, f32 panel

    const int tid = threadIdx.x;
    const int l = tid & 63;
    const int w = tid >> 6;
    const int c = l & 15, hq = l >> 4;
    const int rb = (w >> 2) * 16;
    const int cg = w & 3;
    const int chn = cg >> 1, sb = (cg & 1) * 16;
    const int bbase = blockIdx.x * 8;

    // static staging chunk map: chunk ci = tid + 512*m over [32 rows][75 float4s]
    const int ci1 = tid + 512, ci2 = tid + 1024, ci3 = tid + 1536, ci4 = tid + 2048;
    const int r0 = tid / 75, j0 = tid - 75 * r0;
    const int r1 = ci1 / 75, j1 = ci1 - 75 * r1;
    const int r2 = ci2 / 75, j2 = ci2 - 75 * r2;
    const int r3 = ci3 / 75, j3 = ci3 - 75 * r3;
    const int r4 = ci4 / 75, j4 = ci4 - 75 * r4;
    const bool has4 = (ci4 < 2400);

    const unsigned short* pBh = Bh + (cg * 16 + c) * KP + hq * 8;
    const unsigned short* pBl = Bl + (cg * 16 + c) * KP + hq * 8;

    float4 st0, st1, st2, st3, st4;

    // prologue: gather panel 0
    {
        const int tb = bbase * 32;
        st0 = *(const float4*)(emb + (size_t)tokens[tb + r0] * DIM + j0 * 4);
        st1 = *(const float4*)(emb + (size_t)tokens[tb + r1] * DIM + j1 * 4);
        st2 = *(const float4*)(emb + (size_t)tokens[tb + r2] * DIM + j2 * 4);
        st3 = *(const float4*)(emb + (size_t)tokens[tb + r3] * DIM + j3 * 4);
        if (has4) st4 = *(const float4*)(emb + (size_t)tokens[tb + r4] * DIM + j4 * 4);
    }
    *(float4*)&A[r0 * ASTF + j0 * 4] = st0;
    *(float4*)&A[r1 * ASTF + j1 * 4] = st1;
    *(float4*)&A[r2 * ASTF + j2 * 4] = st2;
    *(float4*)&A[r3 * ASTF + j3 * 4] = st3;
    if (has4) *(float4*)&A[r4 * ASTF + j4 * 4] = st4;
    __syncthreads();

    #pragma unroll 1
    for (int p = 0; p < 8; ++p) {
        // issue next panel's gather (HBM latency hides under this panel's compute)
        if (p < 7) {
            const int tb = (bbase + p + 1) * 32;
            st0 = *(const float4*)(emb + (size_t)tokens[tb + r0] * DIM + j0 * 4);
            st1 = *(const float4*)(emb + (size_t)tokens[tb + r1] * DIM + j1 * 4);
            st2 = *(const float4*)(emb + (size_t)tokens[tb + r2] * DIM + j2 * 4);
            st3 = *(const float4*)(emb + (size_t)tokens[tb + r3] * DIM + j3 * 4);
            if (has4) st4 = *(const float4*)(emb + (size_t)tokens[tb + r4] * DIM + j4 * 4);
        }

        // MFMA over LDS-A (f32 -> in-reg split-bf16) x L2-B
        f32x4 q0 = {0,0,0,0}, q1 = {0,0,0,0}, q2 = {0,0,0,0};
        float nrm = 0.f;
        const float* pA = A + (rb + c) * ASTF + hq * 8;
        #pragma unroll
        for (int t = 0; t < 9; ++t) {
            const float4 c0 = *(const float4*)(pA + t * 32);
            const float4 c1 = *(const float4*)(pA + t * 32 + 4);
            const s16x8 bh = *(const s16x8*)(pBh + t * 32);
            const s16x8 bl = *(const s16x8*)(pBl + t * 32);
            const AB a = cvt_split(c0, c1, nrm);
            q0 = __builtin_amdgcn_mfma_f32_16x16x32_bf16(a.h, bh, q0, 0, 0, 0);
            q1 = __builtin_amdgcn_mfma_f32_16x16x32_bf16(a.h, bl, q1, 0, 0, 0);
            q2 = __builtin_amdgcn_mfma_f32_16x16x32_bf16(a.l, bh, q2, 0, 0, 0);
        }
        {   // t=9: k = 288 + hq*8 ..; valid k<300, mask garbage (LDS in-bounds: row=332 floats)
            const float4 c0 = *(const float4*)(pA + 288);
            const float4 c1 = *(const float4*)(pA + 292);
            float4 d0, d1;
            d0.x = (hq <= 1) ? c0.x : 0.f;
            d0.y = (hq <= 1) ? c0.y : 0.f;
            d0.z = (hq <= 1) ? c0.z : 0.f;
            d0.w = (hq <= 1) ? c0.w : 0.f;
            d1.x = (hq == 0) ? c1.x : 0.f;
            d1.y = (hq == 0) ? c1.y : 0.f;
            d1.z = (hq == 0) ? c1.z : 0.f;
            d1.w = (hq == 0) ? c1.w : 0.f;
            const s16x8 bh = *(const s16x8*)(pBh + 288);
            const s16x8 bl = *(const s16x8*)(pBl + 288);
            const AB a = cvt_split(d0, d1, nrm);
            q0 = __builtin_amdgcn_mfma_f32_16x16x32_bf16(a.h, bh, q0, 0, 0, 0);
            q1 = __builtin_amdgcn_mfma_f32_16x16x32_bf16(a.h, bl, q1, 0, 0, 0);
            q2 = __builtin_amdgcn_mfma_f32_16x16x32_bf16(a.l, bh, q2, 0, 0, 0);
        }

        // row norms (exact f32) + scale + coalesced sm store [b][ch][s][r]
        nrm += __shfl_xor(nrm, 16);
        nrm += __shfl_xor(nrm, 32);            // lane (c,*): |row rb+c|^2
        float4 vv;
        #pragma unroll
        for (int q = 0; q < 4; ++q) {
            const float nq = __shfl(nrm, hq * 4 + q);   // norm of row rb+hq*4+q
            const float rn = __builtin_amdgcn_rcpf(
                fmaxf(__builtin_amdgcn_sqrtf(nq), 1e-8f));
            ((float*)&vv)[q] = (q0[q] + q1[q] + q2[q]) * rn;
        }
        *(float4*)(smG + ((size_t)((bbase + p) * 2 + chn) * 32 + sb + c) * 32 + rb + hq * 4) = vv;

        if (p < 7) {
            __syncthreads();    // all waves done reading A
            *(float4*)&A[r0 * ASTF + j0 * 4] = st0;
            *(float4*)&A[r1 * ASTF + j1 * 4] = st1;
            *(float4*)&A[r2 * ASTF + j2 * 4] = st2;
            *(float4*)&A[r3 * ASTF + j3 * 4] = st3;
            if (has4) *(float4*)&A[r4 * ASTF + j4 * 4] = st4;
            __syncthreads();    // next panel ready
        }
    }
}

// ---------------- kernel 3: tail per batch (softmax-gate + conv1 + conv2 + fc)
__global__ __launch_bounds__(256) void tail_kernel(
    const float* __restrict__ smG,
    const float* __restrict__ c1w, const float* __restrict__ c1b,
    const float* __restrict__ c2w, const float* __restrict__ c2b,
    const float* __restrict__ f2w, const float* __restrict__ f2b,
    const float* __restrict__ fcw, const float* __restrict__ fcb,
    float* __restrict__ out) {

    __shared__ __attribute__((aligned(16))) float smP[34 * SMST];  // [xp=r+1][ch][yp=s+1]
    __shared__ __attribute__((aligned(16))) float pl1P[2 * 17 * 18];
    __shared__ float scrP[8];    // [0..3]=se_w, [4..7]=sv_w

    const int tid = threadIdx.x;
    const int w = tid >> 6, l = tid & 63;
    const int b = blockIdx.x;

    // P0: zero smP + pl1 borders
    {
        const f32x4 z = {0.f, 0.f, 0.f, 0.f};
        #pragma unroll
        for (int i = 0; i < 3; ++i) {
            const int idx = i * 256 + tid;
            if (idx < 697) ((f32x4*)smP)[idx] = z;
        }
        if (tid >= 190) {
            const int z2 = tid - 190;
            const int ic = (z2 >= 33) ? 1 : 0;
            const int rm = z2 - 33 * ic;
            pl1P[ic * 306 + (rm < 17 ? rm : (rm - 16) * 18)] = 0.f;
        }
    }
    __syncthreads();

    // P1: load sm (coalesced) -> padded LDS + fused softmax partials
    {
        const float* src = smG + (size_t)b * 2048;
        float se = 0.f, sv = 0.f;
        #pragma unroll
        for (int h2 = 0; h2 < 2; ++h2) {
            const int f4 = tid * 2 + h2;            // waves 0-1: ch0; waves 2-3: ch1
            const float4 v = ((const float4*)src)[f4];
            const int base = f4 * 4;
            const int chn = base >> 10;
            const int s = (base >> 5) & 31;
            const int r = base & 31;
            float* dstp = &smP[(r + 1) * SMST + chn * SMY + (s + 1)];
            dstp[0] = v.x; dstp[SMST] = v.y; dstp[2 * SMST] = v.z; dstp[3 * SMST] = v.w;
            const float e0 = __expf(v.x), e1 = __expf(v.y);   // |v|<=1: no max-shift
            const float e2 = __expf(v.z), e3 = __expf(v.w);
            se += e0 + e1 + e2 + e3;
            sv = fmaf(e0, v.x, sv); sv = fmaf(e1, v.y, sv);
            sv = fmaf(e2, v.z, sv); sv = fmaf(e3, v.w, sv);
        }
        #pragma unroll
        for (int m = 32; m >= 1; m >>= 1) { se += __shfl_xor(se, m); sv += __shfl_xor(sv, m); }
        if (l == 0) { scrP[w] = se; scrP[4 + w] = sv; }
    }
    __syncthreads();

    // P2: conv1 (both oc per thread) + gate + relu + maxpool -> pl1P
    {
        const int ii = tid >> 4, jj = tid & 15;
        float pc0[4] = {0,0,0,0}, pc1[4] = {0,0,0,0};
        float pA0[4] = {0,0,0,0}, pA1[4] = {0,0,0,0};
        #pragma unroll
        for (int ic = 0; ic < 2; ++ic) {
            float p[4][4];
            #pragma unroll
            for (int a = 0; a < 4; ++a) {        // xp = 2jj+a, yp base 2ii
                const int off = (2 * jj + a) * SMST + ic * SMY + 2 * ii;
                const float2 v01 = *(const float2*)&smP[off];
                const float2 v23 = *(const float2*)&smP[off + 2];
                p[a][0] = v01.x; p[a][1] = v01.y; p[a][2] = v23.x; p[a][3] = v23.y;
            }
            #pragma unroll
            for (int py = 0; py < 2; ++py)
            #pragma unroll
            for (int px = 0; px < 2; ++px)
            #pragma unroll
            for (int dy = 0; dy < 3; ++dy)
            #pragma unroll
            for (int dx = 0; dx < 3; ++dx) {
                const float pv = p[px + dx][py + dy];
                const int pos = py * 2 + px;
                if (ic == 0) {
                    pc0[pos] = fmaf(c1w[0 * 9 + dy * 3 + dx], pv, pc0[pos]);
                    pc1[pos] = fmaf(c1w[2 * 9 + dy * 3 + dx], pv, pc1[pos]);
                } else {
                    pA0[pos] = fmaf(c1w[1 * 9 + dy * 3 + dx], pv, pA0[pos]);
                    pA1[pos] = fmaf(c1w[3 * 9 + dy * 3 + dx], pv, pA1[pos]);
                }
            }
        }
        const float p0 = (scrP[4] + scrP[5]) / (scrP[0] + scrP[1]);
        const float p1 = (scrP[6] + scrP[7]) / (scrP[2] + scrP[3]);
        const float gg0 = 1.f / (1.f + __expf(-(f2w[0] * p0 + f2w[1] * p1 + f2b[0])));
        const float gg1 = 1.f / (1.f + __expf(-(f2w[2] * p0 + f2w[3] * p1 + f2b[1])));
        const float b0 = c1b[0], b1 = c1b[1];
        float mx0 = 0.f, mx1 = 0.f;   // relu folded
        #pragma unroll
        for (int i = 0; i < 4; ++i) {
            mx0 = fmaxf(mx0, b0 + gg0 * pc0[i] + gg1 * pA0[i]);
            mx1 = fmaxf(mx1, b1 + gg0 * pc1[i] + gg1 * pA1[i]);
        }
        pl1P[0 * 306 + (ii + 1) * 18 + (jj + 1)] = mx0;
        pl1P[1 * 306 + (ii + 1) * 18 + (jj + 1)] = mx1;
    }
    __syncthreads();

    // P3: wave 0: conv2(2x2,pad1)+relu+avgpool2 + fc -> out
    if (w == 0) {
        float o0 = 0.f, o1 = 0.f;
        #pragma unroll
        for (int h = 0; h < 2; ++h) {
            const int o = h * 64 + l, oc2 = o >> 6, ii2 = (o >> 3) & 7, jj2 = o & 7;
            float sum = 0.f;
            #pragma unroll
            for (int py = 0; py < 2; ++py)
            #pragma unroll
            for (int px = 0; px < 2; ++px) {
                const int y = 2 * ii2 + py, x = 2 * jj2 + px;
                float acc = c2b[oc2];
                #pragma unroll
                for (int ic = 0; ic < 2; ++ic)
                #pragma unroll
                for (int dy = 0; dy < 2; ++dy)
                #pragma unroll
                for (int dx = 0; dx < 2; ++dx)
                    acc += c2w[((oc2 * 2 + ic) * 2 + dy) * 2 + dx] *
                           pl1P[ic * 306 + (y + dy) * 18 + (x + dx)];
                sum += fmaxf(acc, 0.f);
            }
            const float val = 0.25f * sum;
            o0 = fmaf(val, fcw[o], o0);
            o1 = fmaf(val, fcw[128 + o], o1);
        }
        #pragma unroll
        for (int m = 32; m >= 1; m >>= 1) { o0 += __shfl_xor(o0, m); o1 += __shfl_xor(o1, m); }
        if (l == 0) {
            out[b * 2 + 0] = fcb[0] + o0;
            out[b * 2 + 1] = fcb[1] + o1;
        }
    }
}

extern "C" void kernel_launch(void* const* d_in, const int* in_sizes, int n_in,
                              void* d_out, int out_size, void* d_ws, size_t ws_size,
                              hipStream_t stream) {
    const int* tokens = (const int*)d_in[0];
    const int* sidx   = (const int*)d_in[1];
    const float* emb  = (const float*)d_in[2];
    const float* c1w  = (const float*)d_in[3];
    const float* c1b  = (const float*)d_in[4];
    const float* c2w  = (const float*)d_in[5];
    const float* c2b  = (const float*)d_in[6];
    const float* f2w  = (const float*)d_in[7];
    const float* f2b  = (const float*)d_in[8];
    const float* fcw  = (const float*)d_in[9];
    const float* fcb  = (const float*)d_in[10];

    // ws layout: [sm f32 4096*2*32*32 = 32 MiB][Bh 40 KiB][Bl 40 KiB]
    float* smG = (float*)d_ws;
    unsigned short* Bh = (unsigned short*)((char*)d_ws + (size_t)NBATCH * 2048 * 4);
    unsigned short* Bl = Bh + NSUP * KP;

    prep_kernel<<<NSUP, 64, 0, stream>>>(sidx, emb, Bh, Bl);
    gemm_kernel<<<512, 512, 0, stream>>>(tokens, emb, Bh, Bl, smG);
    tail_kernel<<<NBATCH, 256, 0, stream>>>(smG, c1w, c1b, c2w, c2b,
                                            f2w, f2b, fcw, fcb, (float*)d_out);
}